// Round 20
// baseline (46.846 us; speedup 1.0000x reference)
//
#include <hip/hip_runtime.h>
#include <hip/hip_bf16.h>
#include <math.h>

#define LL 1024
#define DD 512
#define HH 256

typedef __attribute__((ext_vector_type(8))) short bf16x8;
typedef __attribute__((ext_vector_type(4))) float f32x4;

// ws layout (float-slots):
//   O  : [512][1024] bf16 @ 0       rows 0:256 = t(+b1), 256:512 = u   (1 MB)
//   pz : [4][1024][1024] bf16 @ 262144  pairwise h-quarter partials    (8 MB)

__device__ __forceinline__ ushort f2bf(float f) {
  __hip_bfloat16 h = __float2bfloat16(f);
  return *reinterpret_cast<ushort*>(&h);
}
__device__ __forceinline__ float bfu(ushort u) {
  return __uint_as_float(((unsigned int)u) << 16);
}
__device__ __forceinline__ bf16x8 pack8(float4 a, float4 b) {
  bf16x8 r;
  r[0] = (short)f2bf(a.x); r[1] = (short)f2bf(a.y);
  r[2] = (short)f2bf(a.z); r[3] = (short)f2bf(a.w);
  r[4] = (short)f2bf(b.x); r[5] = (short)f2bf(b.y);
  r[6] = (short)f2bf(b.z); r[7] = (short)f2bf(b.w);
  return r;
}

// ---------------------------------------------------------------------------
// Kernel 1: MFMA bf16 GEMM, f32 inputs converted in-register (convert kernel
// deleted -- one fewer dispatch). O[n][i] = sum_k W1row(n)[k]*S[i][k] (+b1,
// n = mat*256+h). Tile 32n x 32i, grid (32,16)=512 blocks (2/CU), 4 waves.
// K=512 = 16 x mfma_f32_16x16x32_bf16. Per step: 4 float4 loads (L2-res)
// + 16 cvt + 1 MFMA. C/D: col=lane&15 (i), row=(lane>>4)*4+reg (n) [m89,
// R18-validated on-device].
// ---------------------------------------------------------------------------
__global__ __launch_bounds__(256) void sp_mgemm(
    const float* __restrict__ S, const float* __restrict__ W1,
    const float* __restrict__ b1, ushort* __restrict__ O) {
  const int tid  = threadIdx.x;
  const int lane = tid & 63;
  const int wv   = tid >> 6;                    // 0..3
  const int i0   = blockIdx.x * 32 + (wv >> 1) * 16;
  const int n0   = blockIdx.y * 32 + (wv & 1) * 16;
  const int lr   = lane & 15;
  const int lg   = lane >> 4;

  const int n  = n0 + lr;
  const float* ap = W1 + (size_t)(n & 255) * (2 * DD) + (n >> 8) * DD + lg * 8;
  const float* bp = S  + (size_t)(i0 + lr) * DD + lg * 8;

  f32x4 acc = {0.f, 0.f, 0.f, 0.f};
  #pragma unroll 4
  for (int ks = 0; ks < 512; ks += 32) {
    const float4 a0 = *(const float4*)(ap + ks);
    const float4 a1 = *(const float4*)(ap + ks + 4);
    const float4 b0 = *(const float4*)(bp + ks);
    const float4 b1v = *(const float4*)(bp + ks + 4);
    acc = __builtin_amdgcn_mfma_f32_16x16x32_bf16(pack8(a0, a1), pack8(b0, b1v),
                                                  acc, 0, 0, 0);
  }

  const bool hasB = (n0 < 256);
  #pragma unroll
  for (int r = 0; r < 4; ++r) {
    const int nn = n0 + lg * 4 + r;
    float v = acc[r];
    if (hasB) v += b1[nn];
    O[(size_t)nn * LL + i0 + lr] = f2bf(v);
  }
}

// ---------------------------------------------------------------------------
// Kernel 2 (R19-proven, verbatim): pairwise, h-split 4, 4i x 4j per thread.
//   pz[z](i,j) = A_z(i) + B_z(j) + sum_{h in z} |t_i+u_j| * w2_h
// 256 thr, tile 64x64, fp32 panels [64][72] x2 = 36.9 KB -> 4 blocks/CU
// = 4 waves/SIMD. grid (16,16,4) = 1024 blocks.
// ---------------------------------------------------------------------------
__global__ __launch_bounds__(256, 4) void sp_pairwise(
    const ushort* __restrict__ O, const float* __restrict__ W2,
    ushort* __restrict__ pz) {
  __shared__ float Tl[64][72];   // 18.4 KB
  __shared__ float Ul[64][72];   // 18.4 KB
  __shared__ float PR[2][128];
  __shared__ float As[64], Bs[64];

  const int tid = threadIdx.x;
  const int tx  = tid & 15;       // j = j0 + 4tx + b
  const int ty  = tid >> 4;       // i = i0 + 4ty + a, ty 0..15
  const int j0  = blockIdx.x * 64;
  const int i0  = blockIdx.y * 64;
  const int hz  = blockIdx.z * 64;

  #pragma unroll
  for (int q = 0; q < 4; ++q) {
    const int m = q * 256 + tid;           // 0..1023
    const int hh = m >> 4;                 // 0..63
    const int g4 = (m & 15) * 4;
    const ushort4 tv = *(const ushort4*)(O + (size_t)(hz + hh) * LL + i0 + g4);
    const ushort4 uv = *(const ushort4*)(O + (size_t)(HH + hz + hh) * LL + j0 + g4);
    *(float4*)&Tl[hh][g4] = make_float4(bfu(tv.x), bfu(tv.y), bfu(tv.z), bfu(tv.w));
    *(float4*)&Ul[hh][g4] = make_float4(bfu(uv.x), bfu(uv.y), bfu(uv.z), bfu(uv.w));
  }
  __syncthreads();

  {
    const int x = tid & 127, hs = tid >> 7;    // hs 0..1
    const float* pan = (x < 64) ? &Tl[0][x] : &Ul[0][x - 64];
    float p = 0.f;
    #pragma unroll 8
    for (int nn = 0; nn < 32; ++nn) {
      const int hh = hs * 32 + nn;
      p = fmaf(pan[hh * 72], W2[hz + hh], p);
    }
    PR[hs][x] = p;
  }
  __syncthreads();
  if (tid < 128) {
    const float s = PR[0][tid] + PR[1][tid];
    if (tid < 64) As[tid] = s; else Bs[tid - 64] = s;
  }
  __syncthreads();

  float acc[4][4] = {{0.f}};

  #pragma unroll 4
  for (int hh = 0; hh < 64; ++hh) {
    const float4 tv4 = *(const float4*)&Tl[hh][4 * ty];
    const float4 uv4 = *(const float4*)&Ul[hh][4 * tx];
    const float w = W2[hz + hh];
    const float tv[4] = {tv4.x, tv4.y, tv4.z, tv4.w};
    const float uv[4] = {uv4.x, uv4.y, uv4.z, uv4.w};
    #pragma unroll
    for (int a = 0; a < 4; ++a) {
      #pragma unroll
      for (int b = 0; b < 4; ++b) {
        acc[a][b] = fmaf(fabsf(tv[a] + uv[b]), w, acc[a][b]);
      }
    }
  }

  ushort* po = pz + (size_t)blockIdx.z * ((size_t)LL * LL);
  #pragma unroll
  for (int a = 0; a < 4; ++a) {
    const float Ai = As[4 * ty + a];
    ushort4 v;
    v.x = f2bf(acc[a][0] + Ai + Bs[4 * tx + 0]);
    v.y = f2bf(acc[a][1] + Ai + Bs[4 * tx + 1]);
    v.z = f2bf(acc[a][2] + Ai + Bs[4 * tx + 2]);
    v.w = f2bf(acc[a][3] + Ai + Bs[4 * tx + 3]);
    *(ushort4*)(po + (size_t)(i0 + 4 * ty + a) * LL + j0 + 4 * tx) = v;
  }
}

// ---------------------------------------------------------------------------
// Kernel 3 (R19-proven, verbatim): out = sigmoid(0.25*(Q + Q^T) + b2),
// Q = pz0+pz1+pz2+pz3 (bf16). 64x64 tiles, grid (16,16), 1024 thr.
// ---------------------------------------------------------------------------
__global__ __launch_bounds__(1024) void sp_symsig(
    const ushort* __restrict__ pz, const float* __restrict__ b2,
    float* __restrict__ out) {
  __shared__ float B[64][65];
  const int i0 = blockIdx.y * 64;
  const int j0 = blockIdx.x * 64;
  const int r  = threadIdx.x >> 4;   // 0..63
  const int g  = threadIdx.x & 15;   // 0..15
  const size_t L2 = (size_t)LL * LL;

  const ushort* pm = pz + (size_t)(j0 + r) * LL + i0 + 4 * g;
  const ushort4 m0 = *(const ushort4*)(pm);
  const ushort4 m1 = *(const ushort4*)(pm + L2);
  const ushort4 m2 = *(const ushort4*)(pm + 2 * L2);
  const ushort4 m3 = *(const ushort4*)(pm + 3 * L2);
  B[r][4 * g + 0] = bfu(m0.x) + bfu(m1.x) + bfu(m2.x) + bfu(m3.x);
  B[r][4 * g + 1] = bfu(m0.y) + bfu(m1.y) + bfu(m2.y) + bfu(m3.y);
  B[r][4 * g + 2] = bfu(m0.z) + bfu(m1.z) + bfu(m2.z) + bfu(m3.z);
  B[r][4 * g + 3] = bfu(m0.w) + bfu(m1.w) + bfu(m2.w) + bfu(m3.w);
  __syncthreads();

  const ushort* pd = pz + (size_t)(i0 + r) * LL + j0 + 4 * g;
  const ushort4 d0 = *(const ushort4*)(pd);
  const ushort4 d1 = *(const ushort4*)(pd + L2);
  const ushort4 d2 = *(const ushort4*)(pd + 2 * L2);
  const ushort4 d3 = *(const ushort4*)(pd + 3 * L2);
  const float bb = b2[0];
  float4 o;
  float x;
  x = 0.25f * (bfu(d0.x) + bfu(d1.x) + bfu(d2.x) + bfu(d3.x) + B[4 * g + 0][r]) + bb;
  o.x = 1.f / (1.f + expf(-x));
  x = 0.25f * (bfu(d0.y) + bfu(d1.y) + bfu(d2.y) + bfu(d3.y) + B[4 * g + 1][r]) + bb;
  o.y = 1.f / (1.f + expf(-x));
  x = 0.25f * (bfu(d0.z) + bfu(d1.z) + bfu(d2.z) + bfu(d3.z) + B[4 * g + 2][r]) + bb;
  o.z = 1.f / (1.f + expf(-x));
  x = 0.25f * (bfu(d0.w) + bfu(d1.w) + bfu(d2.w) + bfu(d3.w) + B[4 * g + 3][r]) + bb;
  o.w = 1.f / (1.f + expf(-x));
  *(float4*)(out + (size_t)(i0 + r) * LL + j0 + 4 * g) = o;
}

// ---------------------------------------------------------------------------
extern "C" void kernel_launch(void* const* d_in, const int* in_sizes, int n_in,
                              void* d_out, int out_size, void* d_ws, size_t ws_size,
                              hipStream_t stream) {
  const float* S  = (const float*)d_in[0];   // [L, D]
  const float* W1 = (const float*)d_in[1];   // [H, 2D]
  const float* b1 = (const float*)d_in[2];   // [H]
  const float* W2 = (const float*)d_in[3];   // [1, H]
  const float* b2 = (const float*)d_in[4];   // [1]
  float* out = (float*)d_out;

  float* ws = (float*)d_ws;
  ushort* O  = (ushort*)ws;                  // [512][1024] bf16
  ushort* pz = (ushort*)(ws + 262144);       // [4][1024][1024] bf16

  hipLaunchKernelGGL(sp_mgemm, dim3(32, 16), dim3(256), 0, stream,
                     S, W1, b1, O);
  hipLaunchKernelGGL(sp_pairwise, dim3(16, 16, 4), dim3(256), 0, stream,
                     O, W2, pz);
  hipLaunchKernelGGL(sp_symsig, dim3(16, 16), dim3(1024), 0, stream,
                     pz, b2, out);
}

// Round 21
// 44.904 us; speedup vs baseline: 1.0432x; 1.0432x over previous
//
#include <hip/hip_runtime.h>
#include <hip/hip_bf16.h>
#include <math.h>

#define LL 1024
#define DD 512
#define HH 256

typedef __attribute__((ext_vector_type(8))) short bf16x8;
typedef __attribute__((ext_vector_type(4))) float f32x4;

// ws layout (float-slots):
//   Sb : [1024][512] bf16 @ 0        S cast to bf16                     (1 MB)
//   Wb : [512][512]  bf16 @ 262144   Wb[n][k] = W1[n&255][(n>>8)*512+k] (0.5 MB)
//   O  : [512][1024] bf16 @ 393216   rows 0:256 = t(+b1), 256:512 = u   (1 MB)
//   pz : [4][1024][1024] bf16 @ 655360  pairwise h-quarter partials     (8 MB)

__device__ __forceinline__ ushort f2bf(float f) {
  __hip_bfloat16 h = __float2bfloat16(f);
  return *reinterpret_cast<ushort*>(&h);
}
__device__ __forceinline__ float bfu(ushort u) {
  return __uint_as_float(((unsigned int)u) << 16);
}

// ---------------------------------------------------------------------------
// Kernel 1 (R18/R19-proven): convert S and W1 to bf16 (Wb rows n = mat*256+h).
// ---------------------------------------------------------------------------
__global__ __launch_bounds__(256) void sp_convert(
    const float* __restrict__ S, const float* __restrict__ W1,
    ushort* __restrict__ Sb, ushort* __restrict__ Wb) {
  const int m = blockIdx.x * 256 + threadIdx.x;   // 0..196607
  const int NS = (LL * DD) / 4;                   // 131072 S float4-groups
  if (m < NS) {
    const float4 v = ((const float4*)S)[m];
    ushort4 o;
    o.x = f2bf(v.x); o.y = f2bf(v.y); o.z = f2bf(v.z); o.w = f2bf(v.w);
    ((ushort4*)Sb)[m] = o;
  } else {
    const int w  = m - NS;          // 0..65535 (Wb float4-groups)
    const int n  = w >> 7;          // 0..511
    const int kg = w & 127;         // k-group of 4
    const float4 v = *(const float4*)(W1 + (size_t)(n & 255) * 1024 +
                                      (n >> 8) * 512 + 4 * kg);
    ushort4 o;
    o.x = f2bf(v.x); o.y = f2bf(v.y); o.z = f2bf(v.z); o.w = f2bf(v.w);
    *(ushort4*)(Wb + (size_t)n * 512 + 4 * kg) = o;
  }
}

// ---------------------------------------------------------------------------
// Kernel 2 (R18/R19-proven): MFMA bf16 GEMM -> O.
// O[n][i] = sum_k Wb[n][k]*Sb[i][k] (+b1 for n<256). Tile 32n x 32i,
// grid (32,16)=512 blocks, 4 waves each. K=512 = 16 x mfma_f32_16x16x32_bf16,
// operands streamed from L2 (Sb+Wb = 1.5 MB resident).
// ---------------------------------------------------------------------------
__global__ __launch_bounds__(256) void sp_mgemm(
    const ushort* __restrict__ Wb, const ushort* __restrict__ Sb,
    const float* __restrict__ b1, ushort* __restrict__ O) {
  const int tid  = threadIdx.x;
  const int lane = tid & 63;
  const int wv   = tid >> 6;                    // 0..3
  const int i0   = blockIdx.x * 32 + (wv >> 1) * 16;
  const int n0   = blockIdx.y * 32 + (wv & 1) * 16;
  const int lr   = lane & 15;
  const int lg   = lane >> 4;

  const ushort* ap = Wb + (size_t)(n0 + lr) * 512 + lg * 8;
  const ushort* bp = Sb + (size_t)(i0 + lr) * 512 + lg * 8;

  f32x4 acc = {0.f, 0.f, 0.f, 0.f};
  #pragma unroll
  for (int ks = 0; ks < 512; ks += 32) {
    const bf16x8 af = *(const bf16x8*)(ap + ks);
    const bf16x8 bf = *(const bf16x8*)(bp + ks);
    acc = __builtin_amdgcn_mfma_f32_16x16x32_bf16(af, bf, acc, 0, 0, 0);
  }

  const bool hasB = (n0 < 256);
  #pragma unroll
  for (int r = 0; r < 4; ++r) {
    const int n = n0 + lg * 4 + r;
    float v = acc[r];
    if (hasB) v += b1[n];
    O[(size_t)n * LL + i0 + lr] = f2bf(v);
  }
}

// ---------------------------------------------------------------------------
// Kernel 3 (R19-proven): pairwise, h-split 4, 4i x 4j per thread.
//   pz[z](i,j) = A_z(i) + B_z(j) + sum_{h in z} |t_i+u_j| * w2_h
// (relu=(x+|x|)/2; 0.25 factor in symsig). 256 thr, tile 64x64.
// fp32 panels [64][72] x2 = 36.9 KB -> 4 blocks/CU = 4 waves/SIMD.
// grid (16,16,4) = 1024 blocks.
// ---------------------------------------------------------------------------
__global__ __launch_bounds__(256, 4) void sp_pairwise(
    const ushort* __restrict__ O, const float* __restrict__ W2,
    ushort* __restrict__ pz) {
  __shared__ float Tl[64][72];   // 18.4 KB
  __shared__ float Ul[64][72];   // 18.4 KB
  __shared__ float PR[2][128];
  __shared__ float As[64], Bs[64];

  const int tid = threadIdx.x;
  const int tx  = tid & 15;       // j = j0 + 4tx + b
  const int ty  = tid >> 4;       // i = i0 + 4ty + a, ty 0..15
  const int j0  = blockIdx.x * 64;
  const int i0  = blockIdx.y * 64;
  const int hz  = blockIdx.z * 64;

  #pragma unroll
  for (int q = 0; q < 4; ++q) {
    const int m = q * 256 + tid;           // 0..1023
    const int hh = m >> 4;                 // 0..63
    const int g4 = (m & 15) * 4;
    const ushort4 tv = *(const ushort4*)(O + (size_t)(hz + hh) * LL + i0 + g4);
    const ushort4 uv = *(const ushort4*)(O + (size_t)(HH + hz + hh) * LL + j0 + g4);
    *(float4*)&Tl[hh][g4] = make_float4(bfu(tv.x), bfu(tv.y), bfu(tv.z), bfu(tv.w));
    *(float4*)&Ul[hh][g4] = make_float4(bfu(uv.x), bfu(uv.y), bfu(uv.z), bfu(uv.w));
  }
  __syncthreads();

  {
    const int x = tid & 127, hs = tid >> 7;    // hs 0..1
    const float* pan = (x < 64) ? &Tl[0][x] : &Ul[0][x - 64];
    float p = 0.f;
    #pragma unroll 8
    for (int nn = 0; nn < 32; ++nn) {
      const int hh = hs * 32 + nn;
      p = fmaf(pan[hh * 72], W2[hz + hh], p);
    }
    PR[hs][x] = p;
  }
  __syncthreads();
  if (tid < 128) {
    const float s = PR[0][tid] + PR[1][tid];
    if (tid < 64) As[tid] = s; else Bs[tid - 64] = s;
  }
  __syncthreads();

  float acc[4][4] = {{0.f}};

  #pragma unroll 4
  for (int hh = 0; hh < 64; ++hh) {
    const float4 tv4 = *(const float4*)&Tl[hh][4 * ty];
    const float4 uv4 = *(const float4*)&Ul[hh][4 * tx];
    const float w = W2[hz + hh];
    const float tv[4] = {tv4.x, tv4.y, tv4.z, tv4.w};
    const float uv[4] = {uv4.x, uv4.y, uv4.z, uv4.w};
    #pragma unroll
    for (int a = 0; a < 4; ++a) {
      #pragma unroll
      for (int b = 0; b < 4; ++b) {
        acc[a][b] = fmaf(fabsf(tv[a] + uv[b]), w, acc[a][b]);
      }
    }
  }

  ushort* po = pz + (size_t)blockIdx.z * ((size_t)LL * LL);
  #pragma unroll
  for (int a = 0; a < 4; ++a) {
    const float Ai = As[4 * ty + a];
    ushort4 v;
    v.x = f2bf(acc[a][0] + Ai + Bs[4 * tx + 0]);
    v.y = f2bf(acc[a][1] + Ai + Bs[4 * tx + 1]);
    v.z = f2bf(acc[a][2] + Ai + Bs[4 * tx + 2]);
    v.w = f2bf(acc[a][3] + Ai + Bs[4 * tx + 3]);
    *(ushort4*)(po + (size_t)(i0 + 4 * ty + a) * LL + j0 + 4 * tx) = v;
  }
}

// ---------------------------------------------------------------------------
// Kernel 4 (R19-proven): out = sigmoid(0.25*(Q + Q^T) + b2),
// Q = pz0+pz1+pz2+pz3 (bf16). 64x64 tiles, grid (16,16), 1024 thr.
// ---------------------------------------------------------------------------
__global__ __launch_bounds__(1024) void sp_symsig(
    const ushort* __restrict__ pz, const float* __restrict__ b2,
    float* __restrict__ out) {
  __shared__ float B[64][65];
  const int i0 = blockIdx.y * 64;
  const int j0 = blockIdx.x * 64;
  const int r  = threadIdx.x >> 4;   // 0..63
  const int g  = threadIdx.x & 15;   // 0..15
  const size_t L2 = (size_t)LL * LL;

  const ushort* pm = pz + (size_t)(j0 + r) * LL + i0 + 4 * g;
  const ushort4 m0 = *(const ushort4*)(pm);
  const ushort4 m1 = *(const ushort4*)(pm + L2);
  const ushort4 m2 = *(const ushort4*)(pm + 2 * L2);
  const ushort4 m3 = *(const ushort4*)(pm + 3 * L2);
  B[r][4 * g + 0] = bfu(m0.x) + bfu(m1.x) + bfu(m2.x) + bfu(m3.x);
  B[r][4 * g + 1] = bfu(m0.y) + bfu(m1.y) + bfu(m2.y) + bfu(m3.y);
  B[r][4 * g + 2] = bfu(m0.z) + bfu(m1.z) + bfu(m2.z) + bfu(m3.z);
  B[r][4 * g + 3] = bfu(m0.w) + bfu(m1.w) + bfu(m2.w) + bfu(m3.w);
  __syncthreads();

  const ushort* pd = pz + (size_t)(i0 + r) * LL + j0 + 4 * g;
  const ushort4 d0 = *(const ushort4*)(pd);
  const ushort4 d1 = *(const ushort4*)(pd + L2);
  const ushort4 d2 = *(const ushort4*)(pd + 2 * L2);
  const ushort4 d3 = *(const ushort4*)(pd + 3 * L2);
  const float bb = b2[0];
  float4 o;
  float x;
  x = 0.25f * (bfu(d0.x) + bfu(d1.x) + bfu(d2.x) + bfu(d3.x) + B[4 * g + 0][r]) + bb;
  o.x = 1.f / (1.f + expf(-x));
  x = 0.25f * (bfu(d0.y) + bfu(d1.y) + bfu(d2.y) + bfu(d3.y) + B[4 * g + 1][r]) + bb;
  o.y = 1.f / (1.f + expf(-x));
  x = 0.25f * (bfu(d0.z) + bfu(d1.z) + bfu(d2.z) + bfu(d3.z) + B[4 * g + 2][r]) + bb;
  o.z = 1.f / (1.f + expf(-x));
  x = 0.25f * (bfu(d0.w) + bfu(d1.w) + bfu(d2.w) + bfu(d3.w) + B[4 * g + 3][r]) + bb;
  o.w = 1.f / (1.f + expf(-x));
  *(float4*)(out + (size_t)(i0 + r) * LL + j0 + 4 * g) = o;
}

// ---------------------------------------------------------------------------
extern "C" void kernel_launch(void* const* d_in, const int* in_sizes, int n_in,
                              void* d_out, int out_size, void* d_ws, size_t ws_size,
                              hipStream_t stream) {
  const float* S  = (const float*)d_in[0];   // [L, D]
  const float* W1 = (const float*)d_in[1];   // [H, 2D]
  const float* b1 = (const float*)d_in[2];   // [H]
  const float* W2 = (const float*)d_in[3];   // [1, H]
  const float* b2 = (const float*)d_in[4];   // [1]
  float* out = (float*)d_out;

  float* ws = (float*)d_ws;
  ushort* Sb = (ushort*)ws;                  // [1024][512] bf16
  ushort* Wb = (ushort*)(ws + 262144);       // [512][512]  bf16
  ushort* O  = (ushort*)(ws + 393216);       // [512][1024] bf16
  ushort* pz = (ushort*)(ws + 655360);       // [4][1024][1024] bf16

  hipLaunchKernelGGL(sp_convert, dim3(768), dim3(256), 0, stream,
                     S, W1, Sb, Wb);
  hipLaunchKernelGGL(sp_mgemm, dim3(32, 16), dim3(256), 0, stream,
                     Wb, Sb, b1, O);
  hipLaunchKernelGGL(sp_pairwise, dim3(16, 16, 4), dim3(256), 0, stream,
                     O, W2, pz);
  hipLaunchKernelGGL(sp_symsig, dim3(16, 16), dim3(1024), 0, stream,
                     pz, b2, out);
}